// Round 5
// baseline (940.841 us; speedup 1.0000x reference)
//
#include <hip/hip_runtime.h>
#include <cstdint>
#include <cstddef>

// Problem constants
constexpr int CB  = 4;
constexpr int CT  = 2048;
constexpr int CD  = 1024;
constexpr int CE  = 4096;
constexpr int CM  = CB * CT;      // 8192 token rows
constexpr int CN2E = 2 * CE;      // 8192
constexpr int NCHUNK = 32;        // per-batch T chunks for scan
constexpr int CLEN = CT / NCHUNK; // 64

typedef float  f32x4  __attribute__((ext_vector_type(4)));
typedef __bf16 bf16x8 __attribute__((ext_vector_type(8)));

__device__ __forceinline__ unsigned short f2bf(float f) {
  unsigned int u = __float_as_uint(f);
  unsigned int r = u + 0x7FFFu + ((u >> 16) & 1u);   // RNE
  return (unsigned short)(r >> 16);
}
__device__ __forceinline__ float bf2f(unsigned short h) {
  return __uint_as_float(((unsigned int)h) << 16);
}

// ---------------- fp32 -> bf16 pack (vectorized x4) ----------------
__global__ __launch_bounds__(256) void k_f2bf4(const float* __restrict__ in,
                                               unsigned short* __restrict__ out, int n4) {
  int i = blockIdx.x * 256 + threadIdx.x;
  if (i >= n4) return;
  float4 v = ((const float4*)in)[i];
  ushort4 o;
  o.x = f2bf(v.x); o.y = f2bf(v.y); o.z = f2bf(v.z); o.w = f2bf(v.w);
  ((ushort4*)out)[i] = o;
}

// ---------------- async global->LDS, 16B per lane ----------------
__device__ __forceinline__ void gll16(const unsigned short* g, void* l) {
  __builtin_amdgcn_global_load_lds(
      (const __attribute__((address_space(1))) void*)g,
      (__attribute__((address_space(3))) void*)l, 16, 0, 0);
}

// =====================================================================
// 256x256 tile, BK=64, 8 waves (2M x 4N), 2-deep LDS double buffer.
// K-tile split into 4 half-tiles {A-klow, B-klow, A-khigh, B-khigh},
// one staged per phase; phases split by (ks, m-half) so the two waits
// per tile are COUNTED vmcnt(4) (drain-0 only at the last tile).
// Only 2 barriers per tile (before ph0 and ph2); phase bodies unfenced.
// LDS per buffer: A[2(ks)][256r][32k] 32KB | B same 32KB; 2 bufs = 128KB.
// Swizzle: phys chunk = logical ^ ((row>>1)&3) -> 2-way on ds_read_b128
// (free); stage keeps LDS dest lane-linear, pre-swizzles the SOURCE k.
// Hazard proof sketch: all stages during tile t write buf[(t+1)&1];
// readers of the overwritten (t-1) data drained lgkm before their MFMA,
// which precedes a fence-barrier that precedes the stage issue.
// EPI 0: bias(b0|b1 @esplit) + silu -> bf16 out0|out1 (ld0 each)
// EPI 1: bias0 -> fp32 out0
// EPI 2: bias0; col<esplit -> sigmoid(-v) else g(v) -> bf16 out0
template <int EPI>
__global__ __launch_bounds__(512, 2) void gemm256(
    const unsigned short* __restrict__ A,   // [M][lda] bf16
    const unsigned short* __restrict__ Bw,  // [N][K]   bf16 (tight)
    const float* __restrict__ bias0,
    const float* __restrict__ bias1,
    void* __restrict__ out0,
    void* __restrict__ out1,
    int M, int N, int K, int lda, int ld0, int esplit) {
  extern __shared__ char lds[];   // 131072 bytes

  const int nbn = N >> 8;
  const int nbm = M >> 8;
  const int nwg = nbm * nbn;
  int bid = blockIdx.x;
  int tau = (bid & 7) * (nwg >> 3) + (bid >> 3);   // XCD chunking (nwg%8==0)
  const int gsz = nbm * 4;                          // group = 4 bn-cols x all bm
  int gg  = tau / gsz;
  int rem = tau - gg * gsz;
  const int bm = rem >> 2;
  const int bn = gg * 4 + (rem & 3);

  const int tid  = threadIdx.x;
  const int lane = tid & 63;
  const int wv   = tid >> 6;
  const int wr   = wv >> 2;       // 0..1
  const int wc   = wv & 3;        // 0..3

  // ---- staging map: thread covers row sr2 (0..127) chunk tid&3 (16B) ----
  const int sr2 = tid >> 2;
  const int scA = (((tid & 3) ^ ((sr2 >> 1) & 3)) * 8);  // swizzled src k-elems

  const unsigned short* Abase = A  + (size_t)bm * 256 * lda;
  const unsigned short* Bbase = Bw + (size_t)bn * 256 * (size_t)K;
  const int NT = K >> 6;
  const int ldsw = wv * 1024;

  // stage one half-tile (matrix off xoff, k-half ks) of tile t: 2 gll16/thread
  auto stage = [&](const unsigned short* Xb, int ldx, int xoff, int t, int ks) {
    char* base = lds + (t & 1) * 65536 + xoff + ks * 16384 + ldsw;
    const unsigned short* g = Xb + (size_t)t * 64 + ks * 32 + scA;
    gll16(g + (size_t)sr2 * ldx, base);
    gll16(g + (size_t)(sr2 + 128) * ldx, base + 8192);
  };

  // ---- fragment read offsets ----
  const int lr = lane & 15, lk = lane >> 4;
  const int rch = (lk ^ ((lr >> 1) & 3)) * 16;           // swizzled chunk byte
  const int aB = (wr * 128 + lr) * 64 + rch;             // + ks*16384 + mf*1024
  const int bB = 32768 + (wc * 64 + lr) * 64 + rch;      // + ks*16384 + nf*1024

  f32x4 acc[8][4];
#pragma unroll
  for (int m = 0; m < 8; m++)
#pragma unroll
    for (int n = 0; n < 4; n++) acc[m][n] = (f32x4){0.f, 0.f, 0.f, 0.f};

  // ---- prologue: stage tile 0, klow halves first ----
  stage(Abase, lda, 0, 0, 0); stage(Bbase, K, 32768, 0, 0);
  stage(Abase, lda, 0, 0, 1); stage(Bbase, K, 32768, 0, 1);

  for (int t = 0; t < NT; t++) {
    const char* bp = lds + (t & 1) * 65536;
    bf16x8 bfr[4], aq[4];
#pragma unroll
    for (int ph = 0; ph < 4; ph++) {
      const int ks = ph >> 1, mh = ph & 1;
      if (mh == 0) {
        // counted wait: 4 youngest stage-ops may remain in flight
        if (t + 1 < NT || ks == 0) asm volatile("s_waitcnt vmcnt(4)" ::: "memory");
        else                       asm volatile("s_waitcnt vmcnt(0)" ::: "memory");
        __builtin_amdgcn_sched_barrier(0);
        __builtin_amdgcn_s_barrier();
        __builtin_amdgcn_sched_barrier(0);
      }
      const int ksb = ks * 16384;
#pragma unroll
      for (int i = 0; i < 4; i++)
        aq[i] = *(const bf16x8*)(bp + ksb + aB + (mh * 4 + i) * 1024);
      if (mh == 0) {
#pragma unroll
        for (int nf = 0; nf < 4; nf++)
          bfr[nf] = *(const bf16x8*)(bp + ksb + bB + nf * 1024);
      }
      if (t + 1 < NT) {
        if      (ph == 0) stage(Abase, lda, 0,     t + 1, 0);
        else if (ph == 1) stage(Bbase, K,   32768, t + 1, 0);
        else if (ph == 2) stage(Abase, lda, 0,     t + 1, 1);
        else              stage(Bbase, K,   32768, t + 1, 1);
      }
      __builtin_amdgcn_s_setprio(1);
#pragma unroll
      for (int i = 0; i < 4; i++)
#pragma unroll
        for (int nf = 0; nf < 4; nf++)
          acc[mh * 4 + i][nf] = __builtin_amdgcn_mfma_f32_16x16x32_bf16(
              aq[i], bfr[nf], acc[mh * 4 + i][nf], 0, 0, 0);
      __builtin_amdgcn_s_setprio(0);
    }
  }

  // ---- epilogue: C/D layout col=lane&15, row=(lane>>4)*4+reg ----
  const int rb = bm * 256 + wr * 128 + (lane >> 4) * 4;
  const int cb = bn * 256 + wc * 64 + (lane & 15);
#pragma unroll
  for (int nf = 0; nf < 4; nf++) {
    const int col = cb + nf * 16;
    float bi;
    if (EPI == 0) bi = (col < esplit) ? bias0[col] : bias1[col - esplit];
    else          bi = bias0[col];
#pragma unroll
    for (int mf = 0; mf < 8; mf++) {
#pragma unroll
      for (int r = 0; r < 4; r++) {
        const int row = rb + mf * 16 + r;
        float v = acc[mf][nf][r] + bi;
        if (EPI == 0) {
          float sg = 1.f / (1.f + __expf(-v));
          unsigned short o = f2bf(v * sg);
          if (col < esplit) ((unsigned short*)out0)[(size_t)row * ld0 + col] = o;
          else              ((unsigned short*)out1)[(size_t)row * ld0 + (col - esplit)] = o;
        } else if (EPI == 1) {
          ((float*)out0)[(size_t)row * ld0 + col] = v;
        } else {  // EPI == 2: gate transform
          unsigned short o;
          if (col < esplit) {
            float e = __expf(-fabsf(v));
            float inv = 1.f / (1.f + e);
            o = f2bf((v >= 0.f) ? e * inv : inv);     // sigmoid(-v)
          } else {
            float gf;
            if (v >= 0.f) gf = v + 0.5f;
            else { float eh = __expf(v); gf = eh / (1.f + eh); }
            o = f2bf(gf);                              // g(v)
          }
          ((unsigned short*)out0)[(size_t)row * ld0 + col] = o;
        }
      }
    }
  }
}

// ---------------- scan pass1 (per batch): A = prod c, B = local recurrence ---
__global__ __launch_bounds__(256) void k_scan1(const unsigned short* __restrict__ ghc,
                                               float* __restrict__ Ac,
                                               float* __restrict__ Bc) {
  int tid = threadIdx.x;
  int lane = tid & 63, cw = tid >> 6;
  int bid = blockIdx.x;
  int eg = bid & 63;
  int cq = bid >> 6;
  int chunk = cq * 4 + cw;
  int e = eg * 64 + lane;
  const unsigned short* cp = ghc + (size_t)(chunk * CLEN) * CN2E + e;
  float h = 0.f, A = 1.f;
#pragma unroll 8
  for (int t = 0; t < CLEN; t++) {
    float c  = bf2f(cp[(size_t)t * CN2E]);
    float gf = bf2f(cp[(size_t)t * CN2E + CE]);
    float v  = (1.f - c) * gf;
    h = __builtin_fmaf(c, h, v);
    A *= c;
  }
  Ac[(size_t)chunk * CE + e] = A;
  Bc[(size_t)chunk * CE + e] = h;
}

// ---------------- scan pass2 (per batch): combine -> exclusive h_start -------
__global__ __launch_bounds__(256) void k_scan2(const float* __restrict__ Ac,
                                               const float* __restrict__ Bc,
                                               float* __restrict__ Hs) {
  int e = blockIdx.x * 256 + threadIdx.x;
  float h = 0.f;
#pragma unroll
  for (int ch = 0; ch < NCHUNK; ch++) {
    Hs[(size_t)ch * CE + e] = h;
    h = __builtin_fmaf(Ac[(size_t)ch * CE + e], h, Bc[(size_t)ch * CE + e]);
  }
}

// ---------------- scan pass3 (per batch): recompute, s = x_skip + h (bf16) ----
__global__ __launch_bounds__(256) void k_scan3(const unsigned short* __restrict__ ghc,
                                               const float* __restrict__ Hs,
                                               const unsigned short* __restrict__ xs,
                                               unsigned short* __restrict__ sp) {
  int tid = threadIdx.x;
  int lane = tid & 63, cw = tid >> 6;
  int bid = blockIdx.x;
  int eg = bid & 63;
  int cq = bid >> 6;
  int chunk = cq * 4 + cw;
  int e = eg * 64 + lane;
  float h = Hs[(size_t)chunk * CE + e];
  const unsigned short* cp  = ghc + (size_t)(chunk * CLEN) * CN2E + e;
  const unsigned short* xsp = xs  + (size_t)(chunk * CLEN) * CE + e;
  unsigned short*       spp = sp  + (size_t)(chunk * CLEN) * CE + e;
#pragma unroll 4
  for (int t = 0; t < CLEN; t++) {
    float c  = bf2f(cp[(size_t)t * CN2E]);
    float gf = bf2f(cp[(size_t)t * CN2E + CE]);
    float v  = (1.f - c) * gf;
    h = __builtin_fmaf(c, h, v);
    float s = h + bf2f(xsp[(size_t)t * CE]);
    spp[(size_t)t * CE] = f2bf(s);
  }
}

// =======================================================================
extern "C" void kernel_launch(void* const* d_in, const int* in_sizes, int n_in,
                              void* d_out, int out_size, void* d_ws, size_t ws_size,
                              hipStream_t stream) {
  const float* x  = (const float*)d_in[0];
  const float* W1 = (const float*)d_in[1];
  const float* b1 = (const float*)d_in[2];
  const float* W2 = (const float*)d_in[3];
  const float* b2 = (const float*)d_in[4];
  const float* Wg = (const float*)d_in[5];
  const float* bg = (const float*)d_in[6];
  const float* Wo = (const float*)d_in[7];
  const float* bo = (const float*)d_in[8];
  float* out = (float*)d_out;

  const size_t MB = 1024 * 1024;
  if (ws_size < 234 * MB) return;   // clean fail instead of fault
  char* ws = (char*)d_ws;
  unsigned short* wgb   = (unsigned short*)(ws);             // 64 MB  Wg bf16 [2E][E]
  unsigned short* wob   = (unsigned short*)(ws + 64 * MB);   //  8 MB  Wo bf16 [D][E]
  unsigned short* wcat  = (unsigned short*)(ws + 72 * MB);   // 16 MB  [W1;W2] (dead after GEMM A)
  unsigned short* xb    = (unsigned short*)(ws + 88 * MB);   // 16 MB  x bf16  (dead after GEMM A)
  unsigned short* ghc   = (unsigned short*)(ws + 72 * MB);   // 32 MB  per-batch coeff|gf (alias)
  unsigned short* xin   = (unsigned short*)(ws + 104 * MB);  // 64 MB  x_in; becomes sbuf
  unsigned short* xskip = (unsigned short*)(ws + 168 * MB);  // 64 MB  x_skip
  float* Ac = (float*)(ws + 232 * MB);
  float* Bc = (float*)(ws + 232 * MB + 512 * 1024);
  float* Hs = (float*)(ws + 233 * MB);

  // allow 128 KB dynamic LDS on the 256^2 kernels (idempotent, non-stream)
  hipFuncSetAttribute(reinterpret_cast<const void*>(&gemm256<0>),
                      hipFuncAttributeMaxDynamicSharedMemorySize, 131072);
  hipFuncSetAttribute(reinterpret_cast<const void*>(&gemm256<1>),
                      hipFuncAttributeMaxDynamicSharedMemorySize, 131072);
  hipFuncSetAttribute(reinterpret_cast<const void*>(&gemm256<2>),
                      hipFuncAttributeMaxDynamicSharedMemorySize, 131072);

  // ---- pack fp32 -> bf16 ----
  {
    int n4;
    n4 = CM * CD / 4;   k_f2bf4<<<n4 / 256, 256, 0, stream>>>(x,  xb,   n4);
    n4 = CE * CD / 4;   k_f2bf4<<<n4 / 256, 256, 0, stream>>>(W1, wcat, n4);
    n4 = CE * CD / 4;   k_f2bf4<<<n4 / 256, 256, 0, stream>>>(W2, wcat + (size_t)CE * CD, n4);
    n4 = CN2E * CE / 4; k_f2bf4<<<n4 / 256, 256, 0, stream>>>(Wg, wgb,  n4);
    n4 = CD * CE / 4;   k_f2bf4<<<n4 / 256, 256, 0, stream>>>(Wo, wob,  n4);
  }

  // ---- GEMM A: [x_in|x_skip] = silu(xb @ wcat^T + [b1|b2]); 8192x8192x1024 ----
  gemm256<0><<<(CM / 256) * (CN2E / 256), 512, 131072, stream>>>(
      xb, wcat, b1, b2, xin, xskip, CM, CN2E, CD, CD, CE, CE);

  // ---- per batch: gate GEMM (2048x8192x4096, +transform epilogue) then scan ----
  for (int b = 0; b < CB; b++) {
    const unsigned short* xin_b = xin + (size_t)b * CT * CE;
    gemm256<2><<<(CT / 256) * (CN2E / 256), 512, 131072, stream>>>(
        xin_b, wgb, bg, nullptr, ghc, nullptr, CT, CN2E, CE, CE, CN2E, CE);
    k_scan1<<<512, 256, 0, stream>>>(ghc, Ac, Bc);
    k_scan2<<<CE / 256, 256, 0, stream>>>(Ac, Bc, Hs);
    k_scan3<<<512, 256, 0, stream>>>(ghc, Hs, xskip + (size_t)b * CT * CE,
                                     xin + (size_t)b * CT * CE);
  }

  // ---- GEMM C: out = sbuf @ Wo^T + bo; 8192x1024x4096 ----
  gemm256<1><<<(CM / 256) * (CD / 256), 512, 131072, stream>>>(
      xin, wob, bo, nullptr, out, nullptr, CM, CD, CE, CE, CD, 0);
}